// Round 1
// baseline (14780.850 us; speedup 1.0000x reference)
//
#include <hip/hip_runtime.h>
#include <cstdint>
#include <cstddef>

// Problem constants (from reference)
#define T_STEPS 16
#define AA 64
#define BBX 64
#define NF 12            // N attention filters
#define BATCH 4096
#define ZS 100
#define ENC 400
#define DEC 400
#define IMG (AA*BBX)     // 4096
#define RDIM (2*NF*NF)   // 288
#define GDIM (4*ENC)     // 1600

__device__ __forceinline__ float sigmoidf_(float v) { return 1.f / (1.f + expf(-v)); }

// ---------------------------------------------------------------------------
// Generic fused-bias GEMM:  C[M x NN] = concat(A0,A1,A2) @ [Wih|Whh]^T + b1(+b2)
//   A pieces are row-major [M x Li]; W row-major [NN x K] split at Ksplit.
// Tile 128x128x16, 256 threads, 8x8 accumulators per thread (fp32 vector ALU;
// no fp32-input MFMA on CDNA4 — bf16-split MFMA is the planned next step).
// ---------------------------------------------------------------------------
#define BM 128
#define BN 128
#define BK 16

__global__ __launch_bounds__(256) void k_gemm(
    const float* __restrict__ A0, int L0,
    const float* __restrict__ A1, int L1,
    const float* __restrict__ A2, int L2,
    const float* __restrict__ Wih, const float* __restrict__ Whh,
    int Ksplit, int K,
    const float* __restrict__ b1, const float* __restrict__ b2,
    float* __restrict__ C, int NN)
{
    __shared__ __align__(16) float At[BK][BM + 4];   // [k][m], stride 132 (2-way conflicts only = free)
    __shared__ __align__(16) float Bt[BK][BN + 4];   // [k][n]
    const int tid = threadIdx.x;
    const int m0 = blockIdx.y * BM;
    const int n0 = blockIdx.x * BN;
    const int tm = tid >> 4, tn = tid & 15;
    const int lr = tid >> 1;            // 0..127: tile row
    const int lc = (tid & 1) * 8;       // 0 or 8: k offset (8 consecutive k per thread = 32B)
    const int L01 = L0 + L1;
    const int L012 = L0 + L1 + L2;
    const int Kh = K - Ksplit;

    float acc[8][8];
#pragma unroll
    for (int i = 0; i < 8; ++i)
#pragma unroll
        for (int j = 0; j < 8; ++j) acc[i][j] = 0.f;

    for (int k0 = 0; k0 < K; k0 += BK) {
        {   // A tile: piecewise-K concat, transposed into LDS
            const int m = m0 + lr;
#pragma unroll
            for (int j = 0; j < 8; ++j) {
                const int k = k0 + lc + j;
                float v = 0.f;
                if (k < L0)        v = A0[(size_t)m * L0 + k];
                else if (k < L01)  v = A1[(size_t)m * L1 + (k - L0)];
                else if (k < L012) v = A2[(size_t)m * L2 + (k - L01)];
                At[lc + j][lr] = v;
            }
        }
        {   // B tile: W^T, piecewise over [Wih|Whh]
            const int n = n0 + lr;
#pragma unroll
            for (int j = 0; j < 8; ++j) {
                const int k = k0 + lc + j;
                float v = 0.f;
                if (n < NN) {
                    if (k < Ksplit)   v = Wih[(size_t)n * Ksplit + k];
                    else if (k < K)   v = Whh[(size_t)n * Kh + (k - Ksplit)];
                }
                Bt[lc + j][lr] = v;
            }
        }
        __syncthreads();
#pragma unroll
        for (int kk = 0; kk < BK; ++kk) {
            const float4 a0 = *(const float4*)&At[kk][tm * 8];
            const float4 a1 = *(const float4*)&At[kk][tm * 8 + 4];
            const float4 b0 = *(const float4*)&Bt[kk][tn * 8];
            const float4 b1v = *(const float4*)&Bt[kk][tn * 8 + 4];
            const float a[8] = {a0.x, a0.y, a0.z, a0.w, a1.x, a1.y, a1.z, a1.w};
            const float b[8] = {b0.x, b0.y, b0.z, b0.w, b1v.x, b1v.y, b1v.z, b1v.w};
#pragma unroll
            for (int i = 0; i < 8; ++i)
#pragma unroll
                for (int j = 0; j < 8; ++j)
                    acc[i][j] += a[i] * b[j];
        }
        __syncthreads();
    }
#pragma unroll
    for (int i = 0; i < 8; ++i) {
        const int m = m0 + tm * 8 + i;
#pragma unroll
        for (int j = 0; j < 8; ++j) {
            const int n = n0 + tn * 8 + j;
            if (n < NN) {
                float v = acc[i][j] + b1[n];
                if (b2) v += b2[n];
                C[(size_t)m * NN + n] = v;
            }
        }
    }
}

// ---------------------------------------------------------------------------
// Attention filterbank: p = hd @ w_attn^T + b_attn; Fx/Fy (12x64) normalized.
// Runs entirely in LDS; caller must __syncthreads() before reading Fx/Fy.
// gamma = expf(p[4]) readable by all threads after return.
// ---------------------------------------------------------------------------
__device__ __forceinline__ void attn_compute(
    const float* __restrict__ hd,          // LDS [DEC]
    const float* __restrict__ w_attn, const float* __restrict__ b_attn,
    float* __restrict__ p,                 // LDS [8]
    float (* __restrict__ Fx)[68], float (* __restrict__ Fy)[68],
    float* __restrict__ rowinv)            // LDS [24]
{
    const int t = threadIdx.x;
    const int lane = t & 63, wave = t >> 6;
    for (int o = wave; o < 5; o += 4) {
        float s = 0.f;
        for (int k = lane; k < DEC; k += 64) s += hd[k] * w_attn[o * DEC + k];
#pragma unroll
        for (int off = 32; off; off >>= 1) s += __shfl_down(s, off);
        if (lane == 0) p[o] = s + b_attn[o];
    }
    __syncthreads();
    const float gx = 32.5f * (p[0] + 1.f);          // (A+1)/2 * (gx_+1)
    const float gy = 32.5f * (p[1] + 1.f);
    const float sigma2 = expf(p[2]);
    const float delta = (63.f / 11.f) * expf(p[3]); // (max(A,B)-1)/(N-1) * exp(ld)
    const float inv2s = 1.f / (2.f * sigma2);
    for (int e = t; e < NF * 64; e += 256) {
        const int n = e >> 6, a = e & 63;
        const float mu_x = ((float)n - 6.5f) * delta + gx;   // half = N/2+0.5
        const float mu_y = ((float)n - 6.5f) * delta + gy;
        const float tx = ((float)a - mu_x) * inv2s;
        const float ty = ((float)a - mu_y) * inv2s;
        Fx[n][a] = expf(-tx * tx);
        Fy[n][a] = expf(-ty * ty);
    }
    __syncthreads();
    for (int rix = wave; rix < 24; rix += 4) {
        const float* row = (rix < 12) ? &Fx[rix][0] : &Fy[rix - 12][0];
        float s = row[lane];
#pragma unroll
        for (int off = 32; off; off >>= 1) s += __shfl_down(s, off);
        if (lane == 0) rowinv[rix] = 1.f / (s + 1e-9f);
    }
    __syncthreads();
    for (int e = t; e < NF * 64; e += 256) {
        const int n = e >> 6, a = e & 63;
        Fx[n][a] *= rowinv[n];
        Fy[n][a] *= rowinv[12 + n];
    }
}

// ---------------------------------------------------------------------------
// Glimpse: attn(h_dec) then r = [gamma*Fy@x@Fx^T, gamma*Fy@x_hat@Fx^T]
// One block per batch item. x_hat = x - sigmoid(canvas) computed on the fly.
// ---------------------------------------------------------------------------
__global__ __launch_bounds__(256) void k_glimpse(
    const float* __restrict__ x, const float* __restrict__ c,
    const float* __restrict__ h_dec,
    const float* __restrict__ w_attn, const float* __restrict__ b_attn,
    float* __restrict__ r_out)
{
    __shared__ __align__(16) float hd[DEC];
    __shared__ __align__(16) float p[8];
    __shared__ __align__(16) float Fx[NF][68], Fy[NF][68];
    __shared__ __align__(16) float rowinv[24];
    __shared__ __align__(16) float img[IMG], imgh[IMG];
    __shared__ __align__(16) float tmp1[NF][68], tmp2[NF][68];
    const int item = blockIdx.x;
    const int t = threadIdx.x;

    for (int i = t; i < DEC; i += 256) hd[i] = h_dec[(size_t)item * DEC + i];
    __syncthreads();
    attn_compute(hd, w_attn, b_attn, p, Fx, Fy, rowinv);

    // load images (overlaps normalize; one barrier covers both)
    for (int i = t; i < IMG; i += 256) {
        const float xv = x[(size_t)item * IMG + i];
        const float cv = c[(size_t)item * IMG + i];
        img[i] = xv;
        imgh[i] = xv - sigmoidf_(cv);
    }
    __syncthreads();
    const float gamma = expf(p[4]);

    // tmp[n][a] = sum_B Fy[n][B] * img[B*64+a]  (both images), float4 over a
    if (t < 192) {
        const int n = t >> 4, a0 = (t & 15) * 4;
        float s10 = 0, s11 = 0, s12 = 0, s13 = 0;
        float s20 = 0, s21 = 0, s22 = 0, s23 = 0;
        for (int Bi = 0; Bi < 64; ++Bi) {
            const float fy = Fy[n][Bi];
            const float4 v1 = *(const float4*)&img[Bi * 64 + a0];
            const float4 v2 = *(const float4*)&imgh[Bi * 64 + a0];
            s10 += fy * v1.x; s11 += fy * v1.y; s12 += fy * v1.z; s13 += fy * v1.w;
            s20 += fy * v2.x; s21 += fy * v2.y; s22 += fy * v2.z; s23 += fy * v2.w;
        }
        *(float4*)&tmp1[n][a0] = make_float4(s10, s11, s12, s13);
        *(float4*)&tmp2[n][a0] = make_float4(s20, s21, s22, s23);
    }
    __syncthreads();

    // g[n][m] = sum_a tmp[n][a] * Fx[m][a];  r[e] layout: [glimpse(x) | glimpse(x_hat)]
    for (int e = t; e < 2 * NF * NF; e += 256) {
        const int which = e / 144;
        const int idx = e - which * 144;
        const int n = idx / 12, m = idx - (idx / 12) * 12;
        const float (*tp)[68] = which ? tmp2 : tmp1;
        const float4* tv = (const float4*)&tp[n][0];
        const float4* fv = (const float4*)&Fx[m][0];
        float s = 0.f;
#pragma unroll
        for (int a4 = 0; a4 < 16; ++a4) {
            const float4 tvv = tv[a4], fvv = fv[a4];
            s += tvv.x * fvv.x + tvv.y * fvv.y + tvv.z * fvv.z + tvv.w * fvv.w;
        }
        r_out[(size_t)item * RDIM + e] = s * gamma;
    }
}

// ---------------------------------------------------------------------------
// LSTM elementwise: gates row [i|f|g|o] (4x400), in-place c/h update.
// ---------------------------------------------------------------------------
__global__ __launch_bounds__(256) void k_lstm(
    const float* __restrict__ gates,
    float* __restrict__ s, float* __restrict__ h)
{
    const int m = blockIdx.y;
    const int n = blockIdx.x * 256 + threadIdx.x;
    if (n >= ENC) return;
    const float* g = gates + (size_t)m * GDIM;
    const float gi = g[n], gf = g[n + 400], gg = g[n + 800], go = g[n + 1200];
    const float cold = s[(size_t)m * ENC + n];
    const float c2 = sigmoidf_(gf) * cold + sigmoidf_(gi) * tanhf(gg);
    s[(size_t)m * ENC + n] = c2;
    h[(size_t)m * ENC + n] = sigmoidf_(go) * tanhf(c2);
}

// z = mu + exp(logsig) * eps ; mus = [mu|logsig] (4096x200)
__global__ __launch_bounds__(256) void k_zelem(
    const float* __restrict__ mus, const float* __restrict__ eps_t,
    float* __restrict__ z)
{
    const int idx = blockIdx.x * 256 + threadIdx.x;
    if (idx >= BATCH * ZS) return;
    const int m = idx / ZS, o = idx - m * ZS;
    z[idx] = mus[(size_t)m * 200 + o] + expf(mus[(size_t)m * 200 + 100 + o]) * eps_t[idx];
}

// ---------------------------------------------------------------------------
// Write: attn(h_dec_new), wr = Fy2^T @ w @ Fx2 / gamma2, canvas += wr.
// wvec = h_dec @ w_write^T + b_write precomputed by k_gemm.
// ---------------------------------------------------------------------------
__global__ __launch_bounds__(256) void k_write(
    const float* __restrict__ h_dec,
    const float* __restrict__ w_attn, const float* __restrict__ b_attn,
    const float* __restrict__ wvec,
    float* __restrict__ c)
{
    __shared__ __align__(16) float hd[DEC];
    __shared__ __align__(16) float p[8];
    __shared__ __align__(16) float Fx[NF][68], Fy[NF][68];
    __shared__ __align__(16) float rowinv[24];
    __shared__ __align__(16) float wsv[NF * NF];
    __shared__ __align__(16) float u[64][13];   // u[B][m] = sum_n Fy[n][B]*w[n][m]
    const int item = blockIdx.x;
    const int t = threadIdx.x;

    for (int i = t; i < DEC; i += 256) hd[i] = h_dec[(size_t)item * DEC + i];
    if (t < NF * NF) wsv[t] = wvec[(size_t)item * (NF * NF) + t];
    __syncthreads();
    attn_compute(hd, w_attn, b_attn, p, Fx, Fy, rowinv);
    __syncthreads();
    const float ginv = 1.f / expf(p[4]);

    for (int e = t; e < 64 * NF; e += 256) {
        const int Bb = e / 12, m = e - (e / 12) * 12;
        float s = 0.f;
#pragma unroll
        for (int n = 0; n < 12; ++n) s += Fy[n][Bb] * wsv[n * 12 + m];
        u[Bb][m] = s;
    }
    __syncthreads();
    for (int i = t; i < IMG; i += 256) {
        const int Bb = i >> 6, a = i & 63;
        float s = 0.f;
#pragma unroll
        for (int m = 0; m < 12; ++m) s += u[Bb][m] * Fx[m][a];
        c[(size_t)item * IMG + i] += s * ginv;
    }
}

// ---------------------------------------------------------------------------
extern "C" void kernel_launch(void* const* d_in, const int* in_sizes, int n_in,
                              void* d_out, int out_size, void* d_ws, size_t ws_size,
                              hipStream_t stream)
{
    const float* x        = (const float*)d_in[0];
    const float* eps      = (const float*)d_in[1];
    const float* w_enc_ih = (const float*)d_in[2];
    const float* w_enc_hh = (const float*)d_in[3];
    const float* b_enc_ih = (const float*)d_in[4];
    const float* b_enc_hh = (const float*)d_in[5];
    const float* w_dec_ih = (const float*)d_in[6];
    const float* w_dec_hh = (const float*)d_in[7];
    const float* b_dec_ih = (const float*)d_in[8];
    const float* b_dec_hh = (const float*)d_in[9];
    const float* w_mu     = (const float*)d_in[10];
    const float* b_mu     = (const float*)d_in[11];
    const float* w_sig    = (const float*)d_in[12];
    const float* b_sig    = (const float*)d_in[13];
    const float* w_attn   = (const float*)d_in[14];
    const float* b_attn   = (const float*)d_in[15];
    const float* w_write  = (const float*)d_in[16];
    const float* b_write  = (const float*)d_in[17];

    float* canvas = (float*)d_out;              // canvas lives in d_out
    float* ws = (float*)d_ws;
    float* h_enc = ws;  ws += (size_t)BATCH * ENC;
    float* s_enc = ws;  ws += (size_t)BATCH * ENC;
    float* h_dec = ws;  ws += (size_t)BATCH * DEC;
    float* s_dec = ws;  ws += (size_t)BATCH * DEC;   // states contiguous for one memset
    float* r     = ws;  ws += (size_t)BATCH * RDIM;
    float* gates = ws;  ws += (size_t)BATCH * GDIM;
    float* mus   = ws;  ws += (size_t)BATCH * 200;
    float* z     = ws;  ws += (size_t)BATCH * ZS;
    float* wvec  = ws;  ws += (size_t)BATCH * (NF * NF);
    float* w_cat = ws;  ws += (size_t)200 * 400;     // [w_mu; w_sig]
    float* b_cat = ws;  ws += 256;                   // [b_mu; b_sig]

    hipMemsetAsync(canvas, 0, (size_t)BATCH * IMG * sizeof(float), stream);
    hipMemsetAsync(h_enc, 0, (size_t)4 * BATCH * ENC * sizeof(float), stream);
    hipMemcpyAsync(w_cat,         w_mu,  (size_t)100 * 400 * 4, hipMemcpyDeviceToDevice, stream);
    hipMemcpyAsync(w_cat + 40000, w_sig, (size_t)100 * 400 * 4, hipMemcpyDeviceToDevice, stream);
    hipMemcpyAsync(b_cat,         b_mu,  100 * 4, hipMemcpyDeviceToDevice, stream);
    hipMemcpyAsync(b_cat + 100,   b_sig, 100 * 4, hipMemcpyDeviceToDevice, stream);

    const dim3 blk(256);
    for (int t = 0; t < T_STEPS; ++t) {
        // 1) glimpse (uses old h_dec, canvas)
        k_glimpse<<<BATCH, blk, 0, stream>>>(x, canvas, h_dec, w_attn, b_attn, r);
        // 2) encoder gates: [r|h_dec|h_enc] @ [w_enc_ih|w_enc_hh]^T + biases
        k_gemm<<<dim3(13, 32), blk, 0, stream>>>(r, RDIM, h_dec, DEC, h_enc, ENC,
            w_enc_ih, w_enc_hh, 688, 1088, b_enc_ih, b_enc_hh, gates, GDIM);
        // 3) encoder LSTM update (in place)
        k_lstm<<<dim3(2, BATCH), blk, 0, stream>>>(gates, s_enc, h_enc);
        // 4) mu/logsig: h_enc @ [w_mu;w_sig]^T
        k_gemm<<<dim3(2, 32), blk, 0, stream>>>(h_enc, ENC, nullptr, 0, nullptr, 0,
            w_cat, nullptr, 400, 400, b_cat, nullptr, mus, 200);
        // 5) z = mu + exp(logsig)*eps_t
        k_zelem<<<dim3((BATCH * ZS + 255) / 256), blk, 0, stream>>>(
            mus, eps + (size_t)t * BATCH * ZS, z);
        // 6) decoder gates: [z|h_dec] @ [w_dec_ih|w_dec_hh]^T + biases
        k_gemm<<<dim3(13, 32), blk, 0, stream>>>(z, ZS, h_dec, DEC, nullptr, 0,
            w_dec_ih, w_dec_hh, 100, 500, b_dec_ih, b_dec_hh, gates, GDIM);
        // 7) decoder LSTM update (in place)
        k_lstm<<<dim3(2, BATCH), blk, 0, stream>>>(gates, s_dec, h_dec);
        // 8) write vector: h_dec_new @ w_write^T + b_write
        k_gemm<<<dim3(2, 32), blk, 0, stream>>>(h_dec, DEC, nullptr, 0, nullptr, 0,
            w_write, nullptr, 400, 400, b_write, nullptr, wvec, NF * NF);
        // 9) write attention + canvas accumulate
        k_write<<<BATCH, blk, 0, stream>>>(h_dec, w_attn, b_attn, wvec, canvas);
    }
}

// Round 2
// 6490.748 us; speedup vs baseline: 2.2772x; 2.2772x over previous
//
#include <hip/hip_runtime.h>
#include <cstdint>
#include <cstddef>

// Problem constants (from reference)
#define T_STEPS 16
#define AA 64
#define BBX 64
#define NF 12            // N attention filters
#define BATCH 4096
#define ZS 100
#define ENC 400
#define DEC 400
#define IMG (AA*BBX)     // 4096
#define RDIM (2*NF*NF)   // 288
#define GDIM (4*ENC)     // 1600

typedef __attribute__((ext_vector_type(8))) short bfrag;    // 8 x bf16 (4 VGPRs)
typedef __attribute__((ext_vector_type(4))) float f32x4;

__device__ __forceinline__ float sigmoidf_(float v) { return 1.f / (1.f + expf(-v)); }

// fp32 -> (bf16_hi, bf16_lo) split, RTN-even. a ~= hi + lo, residual ~2^-18|a|.
__device__ __forceinline__ void split2(float f, unsigned short& h, unsigned short& l) {
    uint32_t u = __builtin_bit_cast(uint32_t, f);
    uint32_t hb = (u + 0x7FFFu + ((u >> 16) & 1u)) >> 16;
    float hf = __builtin_bit_cast(float, hb << 16);
    float r = f - hf;
    uint32_t v = __builtin_bit_cast(uint32_t, r);
    uint32_t lb = (v + 0x7FFFu + ((v >> 16) & 1u)) >> 16;
    h = (unsigned short)hb;
    l = (unsigned short)lb;
}

// ---------------------------------------------------------------------------
// Split-bf16 MFMA GEMM: C[4096 x NN] = concat(A0,A1,A2) @ [Wih|Whh]^T + b1(+b2)
// fp32 in/out; internally each operand split hi+lo bf16, 3 MFMA products:
//   ah*bh + ah*bl + al*bh   (missing al*bl ~ 2^-18 relative)
// Tile: BM=128 (M always 4096), BN=64, BK=32. 256 threads = 4 waves (2x2),
// wave tile 64x32 = 4x2 frags of mfma_f32_16x16x32_bf16.
// LDS layout is fragment-linear: 16x32 subtiles, element (m,k) at
//   sub(m>>4)*512 + ((k>>3)*16 + (m&15))*8 + (k&7)   [ushort units]
// so each frag read is ds_read_b128 at base + lane*16B (conflict-free).
// ---------------------------------------------------------------------------
__global__ __launch_bounds__(256) void k_gemm_mfma(
    const float* __restrict__ A0, int L0,
    const float* __restrict__ A1, int L1,
    const float* __restrict__ A2, int L2,
    const float* __restrict__ Wih, const float* __restrict__ Whh,
    int Ksplit, int K,
    const float* __restrict__ b1, const float* __restrict__ b2,
    float* __restrict__ C, int NN)
{
    __shared__ unsigned short Ah[8 * 512], Al[8 * 512];   // 128x32 bf16 (8 KiB each)
    __shared__ unsigned short Bh[4 * 512], Bl[4 * 512];   // 64x32 bf16 (4 KiB each)

    const int tid = threadIdx.x;
    const int lane = tid & 63;
    const int wave = tid >> 6;
    const int wr = wave >> 1;            // 0..1 : wave row (64 m each)
    const int wc = wave & 1;             // 0..1 : wave col (32 n each)
    const int m0 = blockIdx.y * 128;
    const int n0 = blockIdx.x * 64;
    const int L01 = L0 + L1;
    const int L012 = L0 + L1 + L2;
    const int Kh = K - Ksplit;

    // staging decomposition: thread covers k-quad q (4 consecutive k) of rows r0+32p
    const int q = tid & 7;               // k = q*4 .. q*4+3
    const int r0 = tid >> 3;             // 0..31
    const int kq = q * 4;
    const int e0 = kq & 7;               // elem offset inside 8-elem group (0 or 4)
    const int sel = kq >> 3;             // which 8-elem k-group (0..3)

    f32x4 acc[4][2];
#pragma unroll
    for (int mf = 0; mf < 4; ++mf)
#pragma unroll
        for (int nf = 0; nf < 2; ++nf) acc[mf][nf] = (f32x4){0.f, 0.f, 0.f, 0.f};

    for (int k0 = 0; k0 < K; k0 += 32) {
        // ---- stage A (128x32) ----
#pragma unroll
        for (int p = 0; p < 4; ++p) {
            const int r = r0 + 32 * p;
            const int m = m0 + r;
            const int k = k0 + kq;
            float4 v = make_float4(0.f, 0.f, 0.f, 0.f);
            if (k < L0)        v = *(const float4*)&A0[(size_t)m * L0 + k];
            else if (k < L01)  v = *(const float4*)&A1[(size_t)m * L1 + (k - L0)];
            else if (k < L012) v = *(const float4*)&A2[(size_t)m * L2 + (k - L01)];
            unsigned short h0, h1, h2, h3, l0, l1, l2, l3;
            split2(v.x, h0, l0); split2(v.y, h1, l1);
            split2(v.z, h2, l2); split2(v.w, h3, l3);
            const int base = (r >> 4) * 512 + (sel * 16 + (r & 15)) * 8 + e0;
            uint2 hw, lw;
            hw.x = (uint32_t)h0 | ((uint32_t)h1 << 16);
            hw.y = (uint32_t)h2 | ((uint32_t)h3 << 16);
            lw.x = (uint32_t)l0 | ((uint32_t)l1 << 16);
            lw.y = (uint32_t)l2 | ((uint32_t)l3 << 16);
            *(uint2*)&Ah[base] = hw;
            *(uint2*)&Al[base] = lw;
        }
        // ---- stage B (64x32) from W rows ----
#pragma unroll
        for (int p = 0; p < 2; ++p) {
            const int rn = r0 + 32 * p;
            const int n = n0 + rn;
            const int k = k0 + kq;
            float4 v = make_float4(0.f, 0.f, 0.f, 0.f);
            if (n < NN) {
                if (k < Ksplit)   v = *(const float4*)&Wih[(size_t)n * Ksplit + k];
                else if (k < K)   v = *(const float4*)&Whh[(size_t)n * Kh + (k - Ksplit)];
            }
            unsigned short h0, h1, h2, h3, l0, l1, l2, l3;
            split2(v.x, h0, l0); split2(v.y, h1, l1);
            split2(v.z, h2, l2); split2(v.w, h3, l3);
            const int base = (rn >> 4) * 512 + (sel * 16 + (rn & 15)) * 8 + e0;
            uint2 hw, lw;
            hw.x = (uint32_t)h0 | ((uint32_t)h1 << 16);
            hw.y = (uint32_t)h2 | ((uint32_t)h3 << 16);
            lw.x = (uint32_t)l0 | ((uint32_t)l1 << 16);
            lw.y = (uint32_t)l2 | ((uint32_t)l3 << 16);
            *(uint2*)&Bh[base] = hw;
            *(uint2*)&Bl[base] = lw;
        }
        __syncthreads();

        // ---- compute ----
        bfrag ah[4], al4[4], bh2[2], bl2[2];
#pragma unroll
        for (int mf = 0; mf < 4; ++mf) {
            ah[mf]  = *(const bfrag*)&Ah[(wr * 4 + mf) * 512 + lane * 8];
            al4[mf] = *(const bfrag*)&Al[(wr * 4 + mf) * 512 + lane * 8];
        }
#pragma unroll
        for (int nf = 0; nf < 2; ++nf) {
            bh2[nf] = *(const bfrag*)&Bh[(wc * 2 + nf) * 512 + lane * 8];
            bl2[nf] = *(const bfrag*)&Bl[(wc * 2 + nf) * 512 + lane * 8];
        }
#pragma unroll
        for (int mf = 0; mf < 4; ++mf)
#pragma unroll
            for (int nf = 0; nf < 2; ++nf) {
                acc[mf][nf] = __builtin_amdgcn_mfma_f32_16x16x32_bf16(ah[mf],  bh2[nf], acc[mf][nf], 0, 0, 0);
                acc[mf][nf] = __builtin_amdgcn_mfma_f32_16x16x32_bf16(ah[mf],  bl2[nf], acc[mf][nf], 0, 0, 0);
                acc[mf][nf] = __builtin_amdgcn_mfma_f32_16x16x32_bf16(al4[mf], bh2[nf], acc[mf][nf], 0, 0, 0);
            }
        __syncthreads();
    }

    // ---- epilogue: C layout col=lane&15, row=(lane>>4)*4+j ----
    const int col = lane & 15;
    const int rowq = (lane >> 4) * 4;
#pragma unroll
    for (int nf = 0; nf < 2; ++nf) {
        const int n = n0 + wc * 32 + nf * 16 + col;
        if (n < NN) {
            float bb = b1[n];
            if (b2) bb += b2[n];
#pragma unroll
            for (int mf = 0; mf < 4; ++mf) {
                const int mbase = m0 + wr * 64 + mf * 16 + rowq;
#pragma unroll
                for (int j = 0; j < 4; ++j)
                    C[(size_t)(mbase + j) * NN + n] = acc[mf][nf][j] + bb;
            }
        }
    }
}

// ---------------------------------------------------------------------------
// Attention filterbank: p = hd @ w_attn^T + b_attn; Fx/Fy (12x64) normalized.
// ---------------------------------------------------------------------------
__device__ __forceinline__ void attn_compute(
    const float* __restrict__ hd,          // LDS [DEC]
    const float* __restrict__ w_attn, const float* __restrict__ b_attn,
    float* __restrict__ p,                 // LDS [8]
    float (* __restrict__ Fx)[68], float (* __restrict__ Fy)[68],
    float* __restrict__ rowinv)            // LDS [24]
{
    const int t = threadIdx.x;
    const int lane = t & 63, wave = t >> 6;
    for (int o = wave; o < 5; o += 4) {
        float s = 0.f;
        for (int k = lane; k < DEC; k += 64) s += hd[k] * w_attn[o * DEC + k];
#pragma unroll
        for (int off = 32; off; off >>= 1) s += __shfl_down(s, off);
        if (lane == 0) p[o] = s + b_attn[o];
    }
    __syncthreads();
    const float gx = 32.5f * (p[0] + 1.f);
    const float gy = 32.5f * (p[1] + 1.f);
    const float sigma2 = expf(p[2]);
    const float delta = (63.f / 11.f) * expf(p[3]);
    const float inv2s = 1.f / (2.f * sigma2);
    for (int e = t; e < NF * 64; e += 256) {
        const int n = e >> 6, a = e & 63;
        const float mu_x = ((float)n - 6.5f) * delta + gx;
        const float mu_y = ((float)n - 6.5f) * delta + gy;
        const float tx = ((float)a - mu_x) * inv2s;
        const float ty = ((float)a - mu_y) * inv2s;
        Fx[n][a] = expf(-tx * tx);
        Fy[n][a] = expf(-ty * ty);
    }
    __syncthreads();
    for (int rix = wave; rix < 24; rix += 4) {
        const float* row = (rix < 12) ? &Fx[rix][0] : &Fy[rix - 12][0];
        float s = row[lane];
#pragma unroll
        for (int off = 32; off; off >>= 1) s += __shfl_down(s, off);
        if (lane == 0) rowinv[rix] = 1.f / (s + 1e-9f);
    }
    __syncthreads();
    for (int e = t; e < NF * 64; e += 256) {
        const int n = e >> 6, a = e & 63;
        Fx[n][a] *= rowinv[n];
        Fy[n][a] *= rowinv[12 + n];
    }
}

// ---------------------------------------------------------------------------
// Glimpse: attn(h_dec) then r = [gamma*Fy@x@Fx^T, gamma*Fy@x_hat@Fx^T]
// ---------------------------------------------------------------------------
__global__ __launch_bounds__(256) void k_glimpse(
    const float* __restrict__ x, const float* __restrict__ c,
    const float* __restrict__ h_dec,
    const float* __restrict__ w_attn, const float* __restrict__ b_attn,
    float* __restrict__ r_out)
{
    __shared__ __align__(16) float hd[DEC];
    __shared__ __align__(16) float p[8];
    __shared__ __align__(16) float Fx[NF][68], Fy[NF][68];
    __shared__ __align__(16) float rowinv[24];
    __shared__ __align__(16) float img[IMG], imgh[IMG];
    __shared__ __align__(16) float tmp1[NF][68], tmp2[NF][68];
    const int item = blockIdx.x;
    const int t = threadIdx.x;

    for (int i = t; i < DEC; i += 256) hd[i] = h_dec[(size_t)item * DEC + i];
    __syncthreads();
    attn_compute(hd, w_attn, b_attn, p, Fx, Fy, rowinv);

    for (int i = t; i < IMG; i += 256) {
        const float xv = x[(size_t)item * IMG + i];
        const float cv = c[(size_t)item * IMG + i];
        img[i] = xv;
        imgh[i] = xv - sigmoidf_(cv);
    }
    __syncthreads();
    const float gamma = expf(p[4]);

    if (t < 192) {
        const int n = t >> 4, a0 = (t & 15) * 4;
        float s10 = 0, s11 = 0, s12 = 0, s13 = 0;
        float s20 = 0, s21 = 0, s22 = 0, s23 = 0;
        for (int Bi = 0; Bi < 64; ++Bi) {
            const float fy = Fy[n][Bi];
            const float4 v1 = *(const float4*)&img[Bi * 64 + a0];
            const float4 v2 = *(const float4*)&imgh[Bi * 64 + a0];
            s10 += fy * v1.x; s11 += fy * v1.y; s12 += fy * v1.z; s13 += fy * v1.w;
            s20 += fy * v2.x; s21 += fy * v2.y; s22 += fy * v2.z; s23 += fy * v2.w;
        }
        *(float4*)&tmp1[n][a0] = make_float4(s10, s11, s12, s13);
        *(float4*)&tmp2[n][a0] = make_float4(s20, s21, s22, s23);
    }
    __syncthreads();

    for (int e = t; e < 2 * NF * NF; e += 256) {
        const int which = e / 144;
        const int idx = e - which * 144;
        const int n = idx / 12, m = idx - (idx / 12) * 12;
        const float (*tp)[68] = which ? tmp2 : tmp1;
        const float4* tv = (const float4*)&tp[n][0];
        const float4* fv = (const float4*)&Fx[m][0];
        float s = 0.f;
#pragma unroll
        for (int a4 = 0; a4 < 16; ++a4) {
            const float4 tvv = tv[a4], fvv = fv[a4];
            s += tvv.x * fvv.x + tvv.y * fvv.y + tvv.z * fvv.z + tvv.w * fvv.w;
        }
        r_out[(size_t)item * RDIM + e] = s * gamma;
    }
}

// ---------------------------------------------------------------------------
__global__ __launch_bounds__(256) void k_lstm(
    const float* __restrict__ gates,
    float* __restrict__ s, float* __restrict__ h)
{
    const int m = blockIdx.y;
    const int n = blockIdx.x * 256 + threadIdx.x;
    if (n >= ENC) return;
    const float* g = gates + (size_t)m * GDIM;
    const float gi = g[n], gf = g[n + 400], gg = g[n + 800], go = g[n + 1200];
    const float cold = s[(size_t)m * ENC + n];
    const float c2 = sigmoidf_(gf) * cold + sigmoidf_(gi) * tanhf(gg);
    s[(size_t)m * ENC + n] = c2;
    h[(size_t)m * ENC + n] = sigmoidf_(go) * tanhf(c2);
}

__global__ __launch_bounds__(256) void k_zelem(
    const float* __restrict__ mus, const float* __restrict__ eps_t,
    float* __restrict__ z)
{
    const int idx = blockIdx.x * 256 + threadIdx.x;
    if (idx >= BATCH * ZS) return;
    const int m = idx / ZS, o = idx - m * ZS;
    z[idx] = mus[(size_t)m * 200 + o] + expf(mus[(size_t)m * 200 + 100 + o]) * eps_t[idx];
}

// ---------------------------------------------------------------------------
// Write: attn(h_dec_new), wr = Fy2^T @ w @ Fx2 / gamma2, canvas += wr.
// ---------------------------------------------------------------------------
__global__ __launch_bounds__(256) void k_write(
    const float* __restrict__ h_dec,
    const float* __restrict__ w_attn, const float* __restrict__ b_attn,
    const float* __restrict__ wvec,
    float* __restrict__ c)
{
    __shared__ __align__(16) float hd[DEC];
    __shared__ __align__(16) float p[8];
    __shared__ __align__(16) float Fx[NF][68], Fy[NF][68];
    __shared__ __align__(16) float rowinv[24];
    __shared__ __align__(16) float wsv[NF * NF];
    __shared__ __align__(16) float u[64][13];
    const int item = blockIdx.x;
    const int t = threadIdx.x;

    for (int i = t; i < DEC; i += 256) hd[i] = h_dec[(size_t)item * DEC + i];
    if (t < NF * NF) wsv[t] = wvec[(size_t)item * (NF * NF) + t];
    __syncthreads();
    attn_compute(hd, w_attn, b_attn, p, Fx, Fy, rowinv);
    __syncthreads();
    const float ginv = 1.f / expf(p[4]);

    for (int e = t; e < 64 * NF; e += 256) {
        const int Bb = e / 12, m = e - (e / 12) * 12;
        float s = 0.f;
#pragma unroll
        for (int n = 0; n < 12; ++n) s += Fy[n][Bb] * wsv[n * 12 + m];
        u[Bb][m] = s;
    }
    __syncthreads();
    for (int i = t; i < IMG; i += 256) {
        const int Bb = i >> 6, a = i & 63;
        float s = 0.f;
#pragma unroll
        for (int m = 0; m < 12; ++m) s += u[Bb][m] * Fx[m][a];
        c[(size_t)item * IMG + i] += s * ginv;
    }
}

// ---------------------------------------------------------------------------
extern "C" void kernel_launch(void* const* d_in, const int* in_sizes, int n_in,
                              void* d_out, int out_size, void* d_ws, size_t ws_size,
                              hipStream_t stream)
{
    const float* x        = (const float*)d_in[0];
    const float* eps      = (const float*)d_in[1];
    const float* w_enc_ih = (const float*)d_in[2];
    const float* w_enc_hh = (const float*)d_in[3];
    const float* b_enc_ih = (const float*)d_in[4];
    const float* b_enc_hh = (const float*)d_in[5];
    const float* w_dec_ih = (const float*)d_in[6];
    const float* w_dec_hh = (const float*)d_in[7];
    const float* b_dec_ih = (const float*)d_in[8];
    const float* b_dec_hh = (const float*)d_in[9];
    const float* w_mu     = (const float*)d_in[10];
    const float* b_mu     = (const float*)d_in[11];
    const float* w_sig    = (const float*)d_in[12];
    const float* b_sig    = (const float*)d_in[13];
    const float* w_attn   = (const float*)d_in[14];
    const float* b_attn   = (const float*)d_in[15];
    const float* w_write  = (const float*)d_in[16];
    const float* b_write  = (const float*)d_in[17];

    float* canvas = (float*)d_out;
    float* ws = (float*)d_ws;
    float* h_enc = ws;  ws += (size_t)BATCH * ENC;
    float* s_enc = ws;  ws += (size_t)BATCH * ENC;
    float* h_dec = ws;  ws += (size_t)BATCH * DEC;
    float* s_dec = ws;  ws += (size_t)BATCH * DEC;
    float* r     = ws;  ws += (size_t)BATCH * RDIM;
    float* gates = ws;  ws += (size_t)BATCH * GDIM;
    float* mus   = ws;  ws += (size_t)BATCH * 200;
    float* z     = ws;  ws += (size_t)BATCH * ZS;
    float* wvec  = ws;  ws += (size_t)BATCH * (NF * NF);
    float* w_cat = ws;  ws += (size_t)200 * 400;
    float* b_cat = ws;  ws += 256;

    hipMemsetAsync(canvas, 0, (size_t)BATCH * IMG * sizeof(float), stream);
    hipMemsetAsync(h_enc, 0, (size_t)4 * BATCH * ENC * sizeof(float), stream);
    hipMemcpyAsync(w_cat,         w_mu,  (size_t)100 * 400 * 4, hipMemcpyDeviceToDevice, stream);
    hipMemcpyAsync(w_cat + 40000, w_sig, (size_t)100 * 400 * 4, hipMemcpyDeviceToDevice, stream);
    hipMemcpyAsync(b_cat,         b_mu,  100 * 4, hipMemcpyDeviceToDevice, stream);
    hipMemcpyAsync(b_cat + 100,   b_sig, 100 * 4, hipMemcpyDeviceToDevice, stream);

    const dim3 blk(256);
    for (int t = 0; t < T_STEPS; ++t) {
        // 1) glimpse (uses old h_dec, canvas)
        k_glimpse<<<BATCH, blk, 0, stream>>>(x, canvas, h_dec, w_attn, b_attn, r);
        // 2) encoder gates: [r|h_dec|h_enc] @ [w_enc_ih|w_enc_hh]^T + biases
        k_gemm_mfma<<<dim3(25, 32), blk, 0, stream>>>(r, RDIM, h_dec, DEC, h_enc, ENC,
            w_enc_ih, w_enc_hh, 688, 1088, b_enc_ih, b_enc_hh, gates, GDIM);
        // 3) encoder LSTM update (in place)
        k_lstm<<<dim3(2, BATCH), blk, 0, stream>>>(gates, s_enc, h_enc);
        // 4) mu/logsig: h_enc @ [w_mu;w_sig]^T
        k_gemm_mfma<<<dim3(4, 32), blk, 0, stream>>>(h_enc, ENC, nullptr, 0, nullptr, 0,
            w_cat, nullptr, 400, 400, b_cat, nullptr, mus, 200);
        // 5) z = mu + exp(logsig)*eps_t
        k_zelem<<<dim3((BATCH * ZS + 255) / 256), blk, 0, stream>>>(
            mus, eps + (size_t)t * BATCH * ZS, z);
        // 6) decoder gates: [z|h_dec] @ [w_dec_ih|w_dec_hh]^T + biases
        k_gemm_mfma<<<dim3(25, 32), blk, 0, stream>>>(z, ZS, h_dec, DEC, nullptr, 0,
            w_dec_ih, w_dec_hh, 100, 500, b_dec_ih, b_dec_hh, gates, GDIM);
        // 7) decoder LSTM update (in place)
        k_lstm<<<dim3(2, BATCH), blk, 0, stream>>>(gates, s_dec, h_dec);
        // 8) write vector: h_dec_new @ w_write^T + b_write
        k_gemm_mfma<<<dim3(3, 32), blk, 0, stream>>>(h_dec, DEC, nullptr, 0, nullptr, 0,
            w_write, nullptr, 400, 400, b_write, nullptr, wvec, NF * NF);
        // 9) write attention + canvas accumulate
        k_write<<<BATCH, blk, 0, stream>>>(h_dec, w_attn, b_attn, wvec, canvas);
    }
}

// Round 4
// 4692.318 us; speedup vs baseline: 3.1500x; 1.3833x over previous
//
#include <hip/hip_runtime.h>
#include <cstdint>
#include <cstddef>

// Problem constants (from reference)
#define T_STEPS 16
#define AA 64
#define BBX 64
#define NF 12            // N attention filters
#define BATCH 4096
#define ZS 100
#define ENC 400
#define DEC 400
#define IMG (AA*BBX)     // 4096
#define RDIM (2*NF*NF)   // 288
#define GDIM (4*ENC)     // 1600

// Padded GEMM operand geometry (all K multiples of 32, N multiples of 128)
#define KENC 1088        // [r 0:288 | h_dec 288:688 | h_enc 688:1088]
#define KDEC 544         // [z 0:100 | pad | h_dec 128:528 | pad]
#define KSML 416         // mus / wvec GEMMs (real K=400)
#define NBIG 1664        // padded rows for enc/dec weight B (real 1600)
#define NSML 256         // padded rows for mus/wrt B

typedef __attribute__((ext_vector_type(8))) short bfrag;    // 8 x bf16 (4 VGPRs)
typedef __attribute__((ext_vector_type(4))) float f32x4;

__device__ __forceinline__ float sigmoidf_(float v) { return 1.f / (1.f + expf(-v)); }

__device__ __forceinline__ float bf2f(unsigned short u) {
    uint32_t x = ((uint32_t)u) << 16;
    return __builtin_bit_cast(float, x);
}

// fp32 -> (bf16_hi, bf16_lo) split, RTN-even. f ~= hi + lo, residual ~2^-18|f|.
__device__ __forceinline__ void split2(float f, unsigned short& h, unsigned short& l) {
    uint32_t u = __builtin_bit_cast(uint32_t, f);
    uint32_t hb = (u + 0x7FFFu + ((u >> 16) & 1u)) >> 16;
    float hf = __builtin_bit_cast(float, hb << 16);
    float r = f - hf;
    uint32_t v = __builtin_bit_cast(uint32_t, r);
    uint32_t lb = (v + 0x7FFFu + ((v >> 16) & 1u)) >> 16;
    h = (unsigned short)hb;
    l = (unsigned short)lb;
}

// ---------------------------------------------------------------------------
// Split-bf16 MFMA GEMM, pre-split operands (no conversion in hot loop).
// C[4096 x NN] = A @ B^T + b1(+b2);  A,B given as separate bf16 hi/lo planes.
//   ah*bh + ah*bl + al*bh  (3 products; al*bl ~2^-18 relative, dropped)
// Tile 128x128x32, 256 thr = 4 waves (2x2), wave tile 64x64 = 4x4 frags of
// mfma_f32_16x16x32_bf16. LDS is fragment-linear 16x32 subtiles: element
// (row r, k) of a subtile lives at lane=(k>>3)*16+(r&15), elem k&7 — so both
// global_load_lds (dest = base + lane*16B) and ds_read_b128 are linear.
// Global source per lane: row = base + sub*16 + (lane&15), k = k0+(lane>>4)*8.
// K-padding: B planes are zero-padded to Kpad, so A over-reads hit B zeros.
// ---------------------------------------------------------------------------
__global__ __launch_bounds__(256, 2) void k_gemm2(
    const unsigned short* __restrict__ Ah, const unsigned short* __restrict__ Al,
    int lda, int a_off,
    const unsigned short* __restrict__ Bh, const unsigned short* __restrict__ Bl,
    int Kpad,
    const float* __restrict__ b1, const float* __restrict__ b2,
    float* __restrict__ C, int NN)
{
    __shared__ unsigned short lA[2][8 * 512];   // [hi/lo][sub*512 + lane*8] : 16 KiB
    __shared__ unsigned short lB[2][8 * 512];   // 16 KiB

    const int tid = threadIdx.x;
    const int lane = tid & 63;
    const int wave = tid >> 6;
    const int wr = wave >> 1;                   // wave row (64 m)
    const int wc = wave & 1;                    // wave col (64 n)
    const int m0 = blockIdx.y * 128;
    const int n0 = blockIdx.x * 128;
    const int rlow = lane & 15;
    const int kg8 = (lane >> 4) * 8;

    // per-wave staging source (wave 0:A-hi 1:A-lo 2:B-hi 3:B-lo)
    const size_t aBase = (size_t)(m0 + rlow) * lda + a_off + kg8;
    const size_t bBase = (size_t)(n0 + rlow) * Kpad + kg8;
    const unsigned short* gsrc;
    unsigned short* ldst;
    size_t stride16;                            // 16 rows, in elements
    if (wave == 0)      { gsrc = Ah + aBase; ldst = &lA[0][0]; stride16 = (size_t)lda * 16; }
    else if (wave == 1) { gsrc = Al + aBase; ldst = &lA[1][0]; stride16 = (size_t)lda * 16; }
    else if (wave == 2) { gsrc = Bh + bBase; ldst = &lB[0][0]; stride16 = (size_t)Kpad * 16; }
    else                { gsrc = Bl + bBase; ldst = &lB[1][0]; stride16 = (size_t)Kpad * 16; }

    f32x4 acc[4][4];
#pragma unroll
    for (int mf = 0; mf < 4; ++mf)
#pragma unroll
        for (int nf = 0; nf < 4; ++nf) acc[mf][nf] = (f32x4){0.f, 0.f, 0.f, 0.f};

    for (int k0 = 0; k0 < Kpad; k0 += 32) {
#pragma unroll
        for (int sub = 0; sub < 8; ++sub) {
            __builtin_amdgcn_global_load_lds(
                (const __attribute__((address_space(1))) void*)(gsrc + (size_t)sub * stride16 + k0),
                (__attribute__((address_space(3))) void*)(ldst + sub * 512), 16, 0, 0);
        }
        __syncthreads();   // drains own vmcnt before barrier -> LDS visible to all

        bfrag bhf[4], blf[4];
#pragma unroll
        for (int nf = 0; nf < 4; ++nf) {
            bhf[nf] = *(const bfrag*)&lB[0][(wc * 4 + nf) * 512 + lane * 8];
            blf[nf] = *(const bfrag*)&lB[1][(wc * 4 + nf) * 512 + lane * 8];
        }
#pragma unroll
        for (int mf = 0; mf < 4; ++mf) {
            const bfrag ah = *(const bfrag*)&lA[0][(wr * 4 + mf) * 512 + lane * 8];
            const bfrag al = *(const bfrag*)&lA[1][(wr * 4 + mf) * 512 + lane * 8];
#pragma unroll
            for (int nf = 0; nf < 4; ++nf) {
                acc[mf][nf] = __builtin_amdgcn_mfma_f32_16x16x32_bf16(ah, bhf[nf], acc[mf][nf], 0, 0, 0);
                acc[mf][nf] = __builtin_amdgcn_mfma_f32_16x16x32_bf16(ah, blf[nf], acc[mf][nf], 0, 0, 0);
                acc[mf][nf] = __builtin_amdgcn_mfma_f32_16x16x32_bf16(al, bhf[nf], acc[mf][nf], 0, 0, 0);
            }
        }
        __syncthreads();
    }

    // epilogue: C layout col=lane&15, row=(lane>>4)*4+j
    const int col = lane & 15;
    const int rowq = (lane >> 4) * 4;
#pragma unroll
    for (int nf = 0; nf < 4; ++nf) {
        const int n = n0 + wc * 64 + nf * 16 + col;
        if (n < NN) {
            float bb = b1[n];
            if (b2) bb += b2[n];
#pragma unroll
            for (int mf = 0; mf < 4; ++mf) {
                const int mbase = m0 + wr * 64 + mf * 16 + rowq;
#pragma unroll
                for (int j = 0; j < 4; ++j)
                    C[(size_t)(mbase + j) * NN + n] = acc[mf][nf][j] + bb;
            }
        }
    }
}

// ---------------------------------------------------------------------------
// Weight pre-split: dst[(row0+r)*ld + col0 + c] = split(src[r*cols+c])
// ---------------------------------------------------------------------------
__global__ __launch_bounds__(256) void k_fillw(
    const float* __restrict__ src, int rows, int cols,
    unsigned short* __restrict__ dh, unsigned short* __restrict__ dl,
    int ld, int col0, int row0)
{
    const int i = blockIdx.x * 256 + threadIdx.x;
    if (i >= rows * cols) return;
    const int r = i / cols, c = i - r * cols;
    unsigned short h, l;
    split2(src[i], h, l);
    dh[(size_t)(row0 + r) * ld + col0 + c] = h;
    dl[(size_t)(row0 + r) * ld + col0 + c] = l;
}

// ---------------------------------------------------------------------------
// Attention filterbank: p = hd @ w_attn^T + b_attn; Fx/Fy (12x64) normalized.
// ---------------------------------------------------------------------------
__device__ __forceinline__ void attn_compute(
    const float* __restrict__ hd,
    const float* __restrict__ w_attn, const float* __restrict__ b_attn,
    float* __restrict__ p,
    float (* __restrict__ Fx)[68], float (* __restrict__ Fy)[68],
    float* __restrict__ rowinv)
{
    const int t = threadIdx.x;
    const int lane = t & 63, wave = t >> 6;
    for (int o = wave; o < 5; o += 4) {
        float s = 0.f;
        for (int k = lane; k < DEC; k += 64) s += hd[k] * w_attn[o * DEC + k];
#pragma unroll
        for (int off = 32; off; off >>= 1) s += __shfl_down(s, off);
        if (lane == 0) p[o] = s + b_attn[o];
    }
    __syncthreads();
    const float gx = 32.5f * (p[0] + 1.f);
    const float gy = 32.5f * (p[1] + 1.f);
    const float sigma2 = expf(p[2]);
    const float delta = (63.f / 11.f) * expf(p[3]);
    const float inv2s = 1.f / (2.f * sigma2);
    for (int e = t; e < NF * 64; e += 256) {
        const int n = e >> 6, a = e & 63;
        const float mu_x = ((float)n - 6.5f) * delta + gx;
        const float mu_y = ((float)n - 6.5f) * delta + gy;
        const float tx = ((float)a - mu_x) * inv2s;
        const float ty = ((float)a - mu_y) * inv2s;
        Fx[n][a] = expf(-tx * tx);
        Fy[n][a] = expf(-ty * ty);
    }
    __syncthreads();
    for (int rix = wave; rix < 24; rix += 4) {
        const float* row = (rix < 12) ? &Fx[rix][0] : &Fy[rix - 12][0];
        float s = row[lane];
#pragma unroll
        for (int off = 32; off; off >>= 1) s += __shfl_down(s, off);
        if (lane == 0) rowinv[rix] = 1.f / (s + 1e-9f);
    }
    __syncthreads();
    for (int e = t; e < NF * 64; e += 256) {
        const int n = e >> 6, a = e & 63;
        Fx[n][a] *= rowinv[n];
        Fy[n][a] *= rowinv[12 + n];
    }
}

// ---------------------------------------------------------------------------
// Glimpse: attn(h_dec) then r = [gamma*Fy@x@Fx^T, gamma*Fy@x_hat@Fx^T]
// h_dec read from encA cols 288:688 (hi+lo); r written to encA cols 0:288.
// ---------------------------------------------------------------------------
__global__ __launch_bounds__(256) void k_glimpse(
    const float* __restrict__ x, const float* __restrict__ c,
    unsigned short* __restrict__ eAh, unsigned short* __restrict__ eAl,
    const float* __restrict__ w_attn, const float* __restrict__ b_attn)
{
    __shared__ __align__(16) float hd[DEC];
    __shared__ __align__(16) float p[8];
    __shared__ __align__(16) float Fx[NF][68], Fy[NF][68];
    __shared__ __align__(16) float rowinv[24];
    __shared__ __align__(16) float img[IMG], imgh[IMG];
    __shared__ __align__(16) float tmp1[NF][68], tmp2[NF][68];
    const int item = blockIdx.x;
    const int t = threadIdx.x;
    const size_t arow = (size_t)item * KENC;

    for (int i = t; i < DEC; i += 256)
        hd[i] = bf2f(eAh[arow + 288 + i]) + bf2f(eAl[arow + 288 + i]);
    __syncthreads();
    attn_compute(hd, w_attn, b_attn, p, Fx, Fy, rowinv);

    for (int i = t; i < IMG; i += 256) {
        const float xv = x[(size_t)item * IMG + i];
        const float cv = c[(size_t)item * IMG + i];
        img[i] = xv;
        imgh[i] = xv - sigmoidf_(cv);
    }
    __syncthreads();
    const float gamma = expf(p[4]);

    if (t < 192) {
        const int n = t >> 4, a0 = (t & 15) * 4;
        float s10 = 0, s11 = 0, s12 = 0, s13 = 0;
        float s20 = 0, s21 = 0, s22 = 0, s23 = 0;
        for (int Bi = 0; Bi < 64; ++Bi) {
            const float fy = Fy[n][Bi];
            const float4 v1 = *(const float4*)&img[Bi * 64 + a0];
            const float4 v2 = *(const float4*)&imgh[Bi * 64 + a0];
            s10 += fy * v1.x; s11 += fy * v1.y; s12 += fy * v1.z; s13 += fy * v1.w;
            s20 += fy * v2.x; s21 += fy * v2.y; s22 += fy * v2.z; s23 += fy * v2.w;
        }
        *(float4*)&tmp1[n][a0] = make_float4(s10, s11, s12, s13);
        *(float4*)&tmp2[n][a0] = make_float4(s20, s21, s22, s23);
    }
    __syncthreads();

    for (int e = t; e < 2 * NF * NF; e += 256) {
        const int which = e / 144;
        const int idx = e - which * 144;
        const int n = idx / 12, m = idx - (idx / 12) * 12;
        const float (*tp)[68] = which ? tmp2 : tmp1;
        const float4* tv = (const float4*)&tp[n][0];
        const float4* fv = (const float4*)&Fx[m][0];
        float s = 0.f;
#pragma unroll
        for (int a4 = 0; a4 < 16; ++a4) {
            const float4 tvv = tv[a4], fvv = fv[a4];
            s += tvv.x * fvv.x + tvv.y * fvv.y + tvv.z * fvv.z + tvv.w * fvv.w;
        }
        unsigned short vh, vl;
        split2(s * gamma, vh, vl);
        eAh[arow + e] = vh;
        eAl[arow + e] = vl;
    }
}

// ---------------------------------------------------------------------------
// LSTM elementwise; writes h as bf16 hi/lo into 1 or 2 cat-A destinations.
// ---------------------------------------------------------------------------
__global__ __launch_bounds__(256) void k_lstm(
    const float* __restrict__ gates, float* __restrict__ s,
    unsigned short* __restrict__ d1h, unsigned short* __restrict__ d1l, int ld1,
    unsigned short* __restrict__ d2h, unsigned short* __restrict__ d2l, int ld2)
{
    const int idx = blockIdx.x * 256 + threadIdx.x;
    if (idx >= BATCH * ENC) return;
    const int m = idx / ENC, n = idx - m * ENC;
    const float* g = gates + (size_t)m * GDIM;
    const float gi = g[n], gf = g[n + 400], gg = g[n + 800], go = g[n + 1200];
    const float cold = s[idx];
    const float c2 = sigmoidf_(gf) * cold + sigmoidf_(gi) * tanhf(gg);
    s[idx] = c2;
    const float h = sigmoidf_(go) * tanhf(c2);
    unsigned short hh, hl;
    split2(h, hh, hl);
    d1h[(size_t)m * ld1 + n] = hh;
    d1l[(size_t)m * ld1 + n] = hl;
    if (d2h) {
        d2h[(size_t)m * ld2 + n] = hh;
        d2l[(size_t)m * ld2 + n] = hl;
    }
}

// z = mu + exp(logsig)*eps -> decA cols 0:100 (hi/lo)
__global__ __launch_bounds__(256) void k_zelem(
    const float* __restrict__ mus, const float* __restrict__ eps_t,
    unsigned short* __restrict__ dzh, unsigned short* __restrict__ dzl)
{
    const int idx = blockIdx.x * 256 + threadIdx.x;
    if (idx >= BATCH * ZS) return;
    const int m = idx / ZS, o = idx - m * ZS;
    const float zv = mus[(size_t)m * 200 + o] + expf(mus[(size_t)m * 200 + 100 + o]) * eps_t[idx];
    unsigned short h, l;
    split2(zv, h, l);
    dzh[(size_t)m * KDEC + o] = h;
    dzl[(size_t)m * KDEC + o] = l;
}

// ---------------------------------------------------------------------------
// Write: attn(h_dec_new), wr = Fy2^T @ w @ Fx2 / gamma2, canvas += wr.
// h_dec read from encA cols 288:688 (hi+lo).
// ---------------------------------------------------------------------------
__global__ __launch_bounds__(256) void k_write(
    const unsigned short* __restrict__ eAh, const unsigned short* __restrict__ eAl,
    const float* __restrict__ w_attn, const float* __restrict__ b_attn,
    const float* __restrict__ wvec,
    float* __restrict__ c)
{
    __shared__ __align__(16) float hd[DEC];
    __shared__ __align__(16) float p[8];
    __shared__ __align__(16) float Fx[NF][68], Fy[NF][68];
    __shared__ __align__(16) float rowinv[24];
    __shared__ __align__(16) float wsv[NF * NF];
    __shared__ __align__(16) float u[64][13];
    const int item = blockIdx.x;
    const int t = threadIdx.x;
    const size_t arow = (size_t)item * KENC;

    for (int i = t; i < DEC; i += 256)
        hd[i] = bf2f(eAh[arow + 288 + i]) + bf2f(eAl[arow + 288 + i]);
    if (t < NF * NF) wsv[t] = wvec[(size_t)item * (NF * NF) + t];
    __syncthreads();
    attn_compute(hd, w_attn, b_attn, p, Fx, Fy, rowinv);
    __syncthreads();
    const float ginv = 1.f / expf(p[4]);

    for (int e = t; e < 64 * NF; e += 256) {
        const int Bb = e / 12, m = e - (e / 12) * 12;
        float s = 0.f;
#pragma unroll
        for (int n = 0; n < 12; ++n) s += Fy[n][Bb] * wsv[n * 12 + m];
        u[Bb][m] = s;
    }
    __syncthreads();
    for (int i = t; i < IMG; i += 256) {
        const int Bb = i >> 6, a = i & 63;
        float s = 0.f;
#pragma unroll
        for (int m = 0; m < 12; ++m) s += u[Bb][m] * Fx[m][a];
        c[(size_t)item * IMG + i] += s * ginv;
    }
}

// ---------------------------------------------------------------------------
extern "C" void kernel_launch(void* const* d_in, const int* in_sizes, int n_in,
                              void* d_out, int out_size, void* d_ws, size_t ws_size,
                              hipStream_t stream)
{
    const float* x        = (const float*)d_in[0];
    const float* eps      = (const float*)d_in[1];
    const float* w_enc_ih = (const float*)d_in[2];
    const float* w_enc_hh = (const float*)d_in[3];
    const float* b_enc_ih = (const float*)d_in[4];
    const float* b_enc_hh = (const float*)d_in[5];
    const float* w_dec_ih = (const float*)d_in[6];
    const float* w_dec_hh = (const float*)d_in[7];
    const float* b_dec_ih = (const float*)d_in[8];
    const float* b_dec_hh = (const float*)d_in[9];
    const float* w_mu     = (const float*)d_in[10];
    const float* b_mu     = (const float*)d_in[11];
    const float* w_sig    = (const float*)d_in[12];
    const float* b_sig    = (const float*)d_in[13];
    const float* w_attn   = (const float*)d_in[14];
    const float* b_attn   = (const float*)d_in[15];
    const float* w_write  = (const float*)d_in[16];
    const float* b_write  = (const float*)d_in[17];

    float* canvas = (float*)d_out;

    // ---- workspace layout (256B-aligned chunks) ----
    uint8_t* p = (uint8_t*)d_ws;
    auto nextu = [&](size_t elems) {
        unsigned short* r = (unsigned short*)p;
        p += (elems * 2 + 255) & ~(size_t)255;
        return r;
    };
    auto nextf = [&](size_t elems) {
        float* r = (float*)p;
        p += (elems * 4 + 255) & ~(size_t)255;
        return r;
    };
    uint8_t* zstart = p;
    unsigned short* encA_h = nextu((size_t)(BATCH + 1) * KENC);
    unsigned short* encA_l = nextu((size_t)(BATCH + 1) * KENC);
    unsigned short* decA_h = nextu((size_t)(BATCH + 1) * KDEC);
    unsigned short* decA_l = nextu((size_t)(BATCH + 1) * KDEC);
    unsigned short* encB_h = nextu((size_t)NBIG * KENC);
    unsigned short* encB_l = nextu((size_t)NBIG * KENC);
    unsigned short* decB_h = nextu((size_t)NBIG * KDEC);
    unsigned short* decB_l = nextu((size_t)NBIG * KDEC);
    unsigned short* musB_h = nextu((size_t)NSML * KSML);
    unsigned short* musB_l = nextu((size_t)NSML * KSML);
    unsigned short* wrtB_h = nextu((size_t)NSML * KSML);
    unsigned short* wrtB_l = nextu((size_t)NSML * KSML);
    float* s_enc = nextf((size_t)BATCH * ENC);
    float* s_dec = nextf((size_t)BATCH * DEC);
    float* b_cat = nextf(256);
    uint8_t* zend = p;
    float* gates = nextf((size_t)BATCH * GDIM);
    float* mus   = nextf((size_t)BATCH * 200);
    float* wvec  = nextf((size_t)BATCH * (NF * NF));

    hipMemsetAsync(zstart, 0, (size_t)(zend - zstart), stream);
    hipMemsetAsync(canvas, 0, (size_t)BATCH * IMG * sizeof(float), stream);

    // weight pre-split (runs every launch; ws is re-poisoned each call)
    auto fill = [&](const float* src, int rows, int cols,
                    unsigned short* dh, unsigned short* dl, int ld, int col0, int row0) {
        k_fillw<<<dim3((rows * cols + 255) / 256), 256, 0, stream>>>(
            src, rows, cols, dh, dl, ld, col0, row0);
    };
    fill(w_enc_ih, 1600, 688, encB_h, encB_l, KENC, 0, 0);
    fill(w_enc_hh, 1600, 400, encB_h, encB_l, KENC, 688, 0);
    fill(w_dec_ih, 1600, 100, decB_h, decB_l, KDEC, 0, 0);
    fill(w_dec_hh, 1600, 400, decB_h, decB_l, KDEC, 128, 0);
    fill(w_mu,     100, 400, musB_h, musB_l, KSML, 0, 0);
    fill(w_sig,    100, 400, musB_h, musB_l, KSML, 0, 100);
    fill(w_write,  144, 400, wrtB_h, wrtB_l, KSML, 0, 0);
    hipMemcpyAsync(b_cat,       b_mu,  100 * 4, hipMemcpyDeviceToDevice, stream);
    hipMemcpyAsync(b_cat + 100, b_sig, 100 * 4, hipMemcpyDeviceToDevice, stream);

    const dim3 blk(256);
    for (int t = 0; t < T_STEPS; ++t) {
        // 1) glimpse: reads h_dec(t-1) from encA, canvas; writes r -> encA[:,0:288]
        k_glimpse<<<BATCH, blk, 0, stream>>>(x, canvas, encA_h, encA_l, w_attn, b_attn);
        // 2) encoder gates: encA @ encB^T
        k_gemm2<<<dim3(13, 32), blk, 0, stream>>>(encA_h, encA_l, KENC, 0,
            encB_h, encB_l, KENC, b_enc_ih, b_enc_hh, gates, GDIM);
        // 3) encoder LSTM: h_enc -> encA[:,688:1088]
        k_lstm<<<dim3((BATCH * ENC + 255) / 256), blk, 0, stream>>>(gates, s_enc,
            encA_h + 688, encA_l + 688, KENC, nullptr, nullptr, 0);
        // 4) mu/logsig: h_enc (encA cols 688+) @ musB^T
        k_gemm2<<<dim3(2, 32), blk, 0, stream>>>(encA_h, encA_l, KENC, 688,
            musB_h, musB_l, KSML, b_cat, nullptr, mus, 200);
        // 5) z -> decA[:,0:100]
        k_zelem<<<dim3((BATCH * ZS + 255) / 256), blk, 0, stream>>>(
            mus, eps + (size_t)t * BATCH * ZS, decA_h, decA_l);
        // 6) decoder gates: decA @ decB^T
        k_gemm2<<<dim3(13, 32), blk, 0, stream>>>(decA_h, decA_l, KDEC, 0,
            decB_h, decB_l, KDEC, b_dec_ih, b_dec_hh, gates, GDIM);
        // 7) decoder LSTM: h_dec -> encA[:,288:688] and decA[:,128:528]
        k_lstm<<<dim3((BATCH * ENC + 255) / 256), blk, 0, stream>>>(gates, s_dec,
            encA_h + 288, encA_l + 288, KENC, decA_h + 128, decA_l + 128, KDEC);
        // 8) write vector: h_dec (encA cols 288+) @ wrtB^T
        k_gemm2<<<dim3(2, 32), blk, 0, stream>>>(encA_h, encA_l, KENC, 288,
            wrtB_h, wrtB_l, KSML, b_write, nullptr, wvec, NF * NF);
        // 9) write attention + canvas accumulate
        k_write<<<BATCH, blk, 0, stream>>>(encA_h, encA_l, w_attn, b_attn, wvec, canvas);
    }
}

// Round 6
// 4333.586 us; speedup vs baseline: 3.4108x; 1.0828x over previous
//
#include <hip/hip_runtime.h>
#include <cstdint>
#include <cstddef>

// Problem constants (from reference)
#define T_STEPS 16
#define AA 64
#define BBX 64
#define NF 12            // N attention filters
#define BATCH 4096
#define ZS 100
#define ENC 400
#define DEC 400
#define IMG (AA*BBX)     // 4096
#define RDIM (2*NF*NF)   // 288
#define GDIM (4*ENC)     // 1600

// Padded GEMM operand geometry (all K multiples of 32, N multiples of 128)
#define KENC 1088        // [r 0:288 | h_dec 288:688 | h_enc 688:1088]
#define KDEC 544         // [z 0:100 | pad | h_dec 128:528 | pad]
#define KSML 416         // mus / wvec GEMMs (real K=400)
#define NBIG 1664        // padded rows for enc/dec weight B (real 1600)
#define NSML 256         // padded rows for mus/wrt B

typedef __attribute__((ext_vector_type(8))) short bfrag;    // 8 x bf16 (4 VGPRs)
typedef __attribute__((ext_vector_type(4))) float f32x4;

__device__ __forceinline__ float sigmoidf_(float v) { return 1.f / (1.f + expf(-v)); }

__device__ __forceinline__ float bf2f(unsigned short u) {
    uint32_t x = ((uint32_t)u) << 16;
    return __builtin_bit_cast(float, x);
}

// fp32 -> (bf16_hi, bf16_lo) split, RTN-even. f ~= hi + lo, residual ~2^-18|f|.
__device__ __forceinline__ void split2(float f, unsigned short& h, unsigned short& l) {
    uint32_t u = __builtin_bit_cast(uint32_t, f);
    uint32_t hb = (u + 0x7FFFu + ((u >> 16) & 1u)) >> 16;
    float hf = __builtin_bit_cast(float, hb << 16);
    float r = f - hf;
    uint32_t v = __builtin_bit_cast(uint32_t, r);
    uint32_t lb = (v + 0x7FFFu + ((v >> 16) & 1u)) >> 16;
    h = (unsigned short)hb;
    l = (unsigned short)lb;
}

// LDS-only barrier: does NOT drain vmcnt, so async global_load_lds prefetch
// issued earlier stays in flight across attention compute (T4-style).
__device__ __forceinline__ void bar_lds() {
    asm volatile("s_waitcnt lgkmcnt(0)" ::: "memory");
    __builtin_amdgcn_s_barrier();
    __builtin_amdgcn_sched_barrier(0);
}

// ---------------------------------------------------------------------------
// Split-bf16 MFMA GEMM, pre-split operands (no conversion in hot loop).
// C[4096 x NN] = A @ B^T + b1(+b2);  A,B given as separate bf16 hi/lo planes.
//   ah*bh + ah*bl + al*bh  (3 products; al*bl ~2^-18 relative, dropped)
// Tile 128x128x32, 256 thr = 4 waves (2x2), wave tile 64x64 = 4x4 frags of
// mfma_f32_16x16x32_bf16. LDS fragment-linear 16x32 subtiles (see R3 notes).
// ---------------------------------------------------------------------------
__global__ __launch_bounds__(256, 2) void k_gemm2(
    const unsigned short* __restrict__ Ah, const unsigned short* __restrict__ Al,
    int lda, int a_off,
    const unsigned short* __restrict__ Bh, const unsigned short* __restrict__ Bl,
    int Kpad,
    const float* __restrict__ b1, const float* __restrict__ b2,
    float* __restrict__ C, int NN)
{
    __shared__ unsigned short lA[2][8 * 512];   // [hi/lo][sub*512 + lane*8] : 16 KiB
    __shared__ unsigned short lB[2][8 * 512];   // 16 KiB

    const int tid = threadIdx.x;
    const int lane = tid & 63;
    const int wave = tid >> 6;
    const int wr = wave >> 1;                   // wave row (64 m)
    const int wc = wave & 1;                    // wave col (64 n)
    const int m0 = blockIdx.y * 128;
    const int n0 = blockIdx.x * 128;
    const int rlow = lane & 15;
    const int kg8 = (lane >> 4) * 8;

    // per-wave staging source (wave 0:A-hi 1:A-lo 2:B-hi 3:B-lo)
    const size_t aBase = (size_t)(m0 + rlow) * lda + a_off + kg8;
    const size_t bBase = (size_t)(n0 + rlow) * Kpad + kg8;
    const unsigned short* gsrc;
    unsigned short* ldst;
    size_t stride16;                            // 16 rows, in elements
    if (wave == 0)      { gsrc = Ah + aBase; ldst = &lA[0][0]; stride16 = (size_t)lda * 16; }
    else if (wave == 1) { gsrc = Al + aBase; ldst = &lA[1][0]; stride16 = (size_t)lda * 16; }
    else if (wave == 2) { gsrc = Bh + bBase; ldst = &lB[0][0]; stride16 = (size_t)Kpad * 16; }
    else                { gsrc = Bl + bBase; ldst = &lB[1][0]; stride16 = (size_t)Kpad * 16; }

    f32x4 acc[4][4];
#pragma unroll
    for (int mf = 0; mf < 4; ++mf)
#pragma unroll
        for (int nf = 0; nf < 4; ++nf) acc[mf][nf] = (f32x4){0.f, 0.f, 0.f, 0.f};

    for (int k0 = 0; k0 < Kpad; k0 += 32) {
#pragma unroll
        for (int sub = 0; sub < 8; ++sub) {
            __builtin_amdgcn_global_load_lds(
                (const __attribute__((address_space(1))) void*)(gsrc + (size_t)sub * stride16 + k0),
                (__attribute__((address_space(3))) void*)(ldst + sub * 512), 16, 0, 0);
        }
        __syncthreads();   // drains own vmcnt before barrier -> LDS visible to all

        bfrag bhf[4], blf[4];
#pragma unroll
        for (int nf = 0; nf < 4; ++nf) {
            bhf[nf] = *(const bfrag*)&lB[0][(wc * 4 + nf) * 512 + lane * 8];
            blf[nf] = *(const bfrag*)&lB[1][(wc * 4 + nf) * 512 + lane * 8];
        }
#pragma unroll
        for (int mf = 0; mf < 4; ++mf) {
            const bfrag ah = *(const bfrag*)&lA[0][(wr * 4 + mf) * 512 + lane * 8];
            const bfrag al = *(const bfrag*)&lA[1][(wr * 4 + mf) * 512 + lane * 8];
#pragma unroll
            for (int nf = 0; nf < 4; ++nf) {
                acc[mf][nf] = __builtin_amdgcn_mfma_f32_16x16x32_bf16(ah, bhf[nf], acc[mf][nf], 0, 0, 0);
                acc[mf][nf] = __builtin_amdgcn_mfma_f32_16x16x32_bf16(ah, blf[nf], acc[mf][nf], 0, 0, 0);
                acc[mf][nf] = __builtin_amdgcn_mfma_f32_16x16x32_bf16(al, bhf[nf], acc[mf][nf], 0, 0, 0);
            }
        }
        __syncthreads();
    }

    // epilogue: C layout col=lane&15, row=(lane>>4)*4+j
    const int col = lane & 15;
    const int rowq = (lane >> 4) * 4;
#pragma unroll
    for (int nf = 0; nf < 4; ++nf) {
        const int n = n0 + wc * 64 + nf * 16 + col;
        if (n < NN) {
            float bb = b1[n];
            if (b2) bb += b2[n];
#pragma unroll
            for (int mf = 0; mf < 4; ++mf) {
                const int mbase = m0 + wr * 64 + mf * 16 + rowq;
#pragma unroll
                for (int j = 0; j < 4; ++j)
                    C[(size_t)(mbase + j) * NN + n] = acc[mf][nf][j] + bb;
            }
        }
    }
}

// ---------------------------------------------------------------------------
// Weight pre-split: dst[(row0+r)*ld + col0 + c] = split(src[r*cols+c])
// ---------------------------------------------------------------------------
__global__ __launch_bounds__(256) void k_fillw(
    const float* __restrict__ src, int rows, int cols,
    unsigned short* __restrict__ dh, unsigned short* __restrict__ dl,
    int ld, int col0, int row0)
{
    const int i = blockIdx.x * 256 + threadIdx.x;
    if (i >= rows * cols) return;
    const int r = i / cols, c = i - r * cols;
    unsigned short h, l;
    split2(src[i], h, l);
    dh[(size_t)(row0 + r) * ld + col0 + c] = h;
    dl[(size_t)(row0 + r) * ld + col0 + c] = l;
}

// ---------------------------------------------------------------------------
// Attention filterbank (barrier-flavor duplicated: full-sync and lgkm-only).
// p = hd @ w_attn^T + b_attn; Fx/Fy (12x64) normalized rows.
// ---------------------------------------------------------------------------
__device__ __forceinline__ void attn_compute(
    const float* __restrict__ hd,
    const float* __restrict__ w_attn, const float* __restrict__ b_attn,
    float* __restrict__ p,
    float (* __restrict__ Fx)[68], float (* __restrict__ Fy)[68],
    float* __restrict__ rowinv)
{
    const int t = threadIdx.x;
    const int lane = t & 63, wave = t >> 6;
    for (int o = wave; o < 5; o += 4) {
        float s = 0.f;
        for (int k = lane; k < DEC; k += 64) s += hd[k] * w_attn[o * DEC + k];
#pragma unroll
        for (int off = 32; off; off >>= 1) s += __shfl_down(s, off);
        if (lane == 0) p[o] = s + b_attn[o];
    }
    __syncthreads();
    const float gx = 32.5f * (p[0] + 1.f);
    const float gy = 32.5f * (p[1] + 1.f);
    const float sigma2 = expf(p[2]);
    const float delta = (63.f / 11.f) * expf(p[3]);
    const float inv2s = 1.f / (2.f * sigma2);
    for (int e = t; e < NF * 64; e += 256) {
        const int n = e >> 6, a = e & 63;
        const float mu_x = ((float)n - 6.5f) * delta + gx;
        const float mu_y = ((float)n - 6.5f) * delta + gy;
        const float tx = ((float)a - mu_x) * inv2s;
        const float ty = ((float)a - mu_y) * inv2s;
        Fx[n][a] = expf(-tx * tx);
        Fy[n][a] = expf(-ty * ty);
    }
    __syncthreads();
    for (int rix = wave; rix < 24; rix += 4) {
        const float* row = (rix < 12) ? &Fx[rix][0] : &Fy[rix - 12][0];
        float s = row[lane];
#pragma unroll
        for (int off = 32; off; off >>= 1) s += __shfl_down(s, off);
        if (lane == 0) rowinv[rix] = 1.f / (s + 1e-9f);
    }
    __syncthreads();
    for (int e = t; e < NF * 64; e += 256) {
        const int n = e >> 6, a = e & 63;
        Fx[n][a] *= rowinv[n];
        Fy[n][a] *= rowinv[12 + n];
    }
}

// Same math, but LDS-only barriers (keeps async prefetch in flight).
__device__ __forceinline__ void attn_compute_nb(
    const float* __restrict__ hd,
    const float* __restrict__ w_attn, const float* __restrict__ b_attn,
    float* __restrict__ p,
    float (* __restrict__ Fx)[68], float (* __restrict__ Fy)[68],
    float* __restrict__ rowinv)
{
    const int t = threadIdx.x;
    const int lane = t & 63, wave = t >> 6;
    for (int o = wave; o < 5; o += 4) {
        float s = 0.f;
        for (int k = lane; k < DEC; k += 64) s += hd[k] * w_attn[o * DEC + k];
#pragma unroll
        for (int off = 32; off; off >>= 1) s += __shfl_down(s, off);
        if (lane == 0) p[o] = s + b_attn[o];
    }
    bar_lds();
    const float gx = 32.5f * (p[0] + 1.f);
    const float gy = 32.5f * (p[1] + 1.f);
    const float sigma2 = expf(p[2]);
    const float delta = (63.f / 11.f) * expf(p[3]);
    const float inv2s = 1.f / (2.f * sigma2);
    for (int e = t; e < NF * 64; e += 256) {
        const int n = e >> 6, a = e & 63;
        const float mu_x = ((float)n - 6.5f) * delta + gx;
        const float mu_y = ((float)n - 6.5f) * delta + gy;
        const float tx = ((float)a - mu_x) * inv2s;
        const float ty = ((float)a - mu_y) * inv2s;
        Fx[n][a] = expf(-tx * tx);
        Fy[n][a] = expf(-ty * ty);
    }
    bar_lds();
    for (int rix = wave; rix < 24; rix += 4) {
        const float* row = (rix < 12) ? &Fx[rix][0] : &Fy[rix - 12][0];
        float s = row[lane];
#pragma unroll
        for (int off = 32; off; off >>= 1) s += __shfl_down(s, off);
        if (lane == 0) rowinv[rix] = 1.f / (s + 1e-9f);
    }
    bar_lds();
    for (int e = t; e < NF * 64; e += 256) {
        const int n = e >> 6, a = e & 63;
        Fx[n][a] *= rowinv[n];
        Fy[n][a] *= rowinv[12 + n];
    }
}

// ---------------------------------------------------------------------------
// Glimpse (step 0 only): attn(h_dec) then r = [g*Fy@x@Fx^T, g*Fy@x_hat@Fx^T]
// ---------------------------------------------------------------------------
__global__ __launch_bounds__(256) void k_glimpse(
    const float* __restrict__ x, const float* __restrict__ c,
    unsigned short* __restrict__ eAh, unsigned short* __restrict__ eAl,
    const float* __restrict__ w_attn, const float* __restrict__ b_attn)
{
    __shared__ __align__(16) float hd[DEC];
    __shared__ __align__(16) float p[8];
    __shared__ __align__(16) float Fx[NF][68], Fy[NF][68];
    __shared__ __align__(16) float rowinv[24];
    __shared__ __align__(16) float img[IMG], imgh[IMG];
    __shared__ __align__(16) float tmp1[NF][68], tmp2[NF][68];
    const int item = blockIdx.x;
    const int t = threadIdx.x;
    const size_t arow = (size_t)item * KENC;

    for (int i = t; i < DEC; i += 256)
        hd[i] = bf2f(eAh[arow + 288 + i]) + bf2f(eAl[arow + 288 + i]);
    __syncthreads();
    attn_compute(hd, w_attn, b_attn, p, Fx, Fy, rowinv);

    for (int i = t; i < IMG; i += 256) {
        const float xv = x[(size_t)item * IMG + i];
        const float cv = c[(size_t)item * IMG + i];
        img[i] = xv;
        imgh[i] = xv - sigmoidf_(cv);
    }
    __syncthreads();
    const float gamma = expf(p[4]);

    if (t < 192) {
        const int n = t >> 4, a0 = (t & 15) * 4;
        float s10 = 0, s11 = 0, s12 = 0, s13 = 0;
        float s20 = 0, s21 = 0, s22 = 0, s23 = 0;
        for (int Bi = 0; Bi < 64; ++Bi) {
            const float fy = Fy[n][Bi];
            const float4 v1 = *(const float4*)&img[Bi * 64 + a0];
            const float4 v2 = *(const float4*)&imgh[Bi * 64 + a0];
            s10 += fy * v1.x; s11 += fy * v1.y; s12 += fy * v1.z; s13 += fy * v1.w;
            s20 += fy * v2.x; s21 += fy * v2.y; s22 += fy * v2.z; s23 += fy * v2.w;
        }
        *(float4*)&tmp1[n][a0] = make_float4(s10, s11, s12, s13);
        *(float4*)&tmp2[n][a0] = make_float4(s20, s21, s22, s23);
    }
    __syncthreads();

    for (int e = t; e < 2 * NF * NF; e += 256) {
        const int which = e / 144;
        const int idx = e - which * 144;
        const int n = idx / 12, m = idx - (idx / 12) * 12;
        const float (*tp)[68] = which ? tmp2 : tmp1;
        const float4* tv = (const float4*)&tp[n][0];
        const float4* fv = (const float4*)&Fx[m][0];
        float s = 0.f;
#pragma unroll
        for (int a4 = 0; a4 < 16; ++a4) {
            const float4 tvv = tv[a4], fvv = fv[a4];
            s += tvv.x * fvv.x + tvv.y * fvv.y + tvv.z * fvv.z + tvv.w * fvv.w;
        }
        unsigned short vh, vl;
        split2(s * gamma, vh, vl);
        eAh[arow + e] = vh;
        eAl[arow + e] = vl;
    }
}

// ---------------------------------------------------------------------------
// FUSED write(t) + glimpse(t+1).  Both use attn(h_dec(t)) — computed ONCE.
//   phase 0: async prefetch x,canvas -> LDS (global_load_lds, in flight
//            through attention); load h_dec.
//   phase 1: attn (lgkm-only barriers), u = Fy^T-weighted wvec.
//   phase 2: full sync (drains vmcnt); c_new = c + wr/gamma (float4 store),
//            imgh = x - sigmoid(c_new) overwrites canvas slab.
//   phase 3: glimpse contraction; r(t+1) -> encA (bf16 hi/lo).
// ---------------------------------------------------------------------------
__global__ __launch_bounds__(256) void k_wrgl(
    const float* __restrict__ x, float* __restrict__ c,
    unsigned short* __restrict__ eAh, unsigned short* __restrict__ eAl,
    const float* __restrict__ w_attn, const float* __restrict__ b_attn,
    const float* __restrict__ wvec)
{
    __shared__ __align__(16) float xx[IMG];      // x            (16 KiB)
    __shared__ __align__(16) float cc[IMG];      // canvas->imgh (16 KiB)
    __shared__ __align__(16) float hd[DEC];
    __shared__ __align__(16) float p[8];
    __shared__ __align__(16) float Fx[NF][68], Fy[NF][68];
    __shared__ __align__(16) float rowinv[24];
    __shared__ __align__(16) float wsv[NF * NF];
    __shared__ __align__(16) float u[64][13];
    __shared__ __align__(16) float tmp1[NF][68], tmp2[NF][68];
    const int item = blockIdx.x;
    const int t = threadIdx.x;
    const int lane = t & 63, wave = t >> 6;
    const size_t arow = (size_t)item * KENC;

    // --- phase 0: register loads first, then async LDS prefetch ---
    float hdv0 = 0.f, hdv1 = 0.f, wv0 = 0.f;
    {
        const int i0 = t, i1 = t + 256;
        hdv0 = bf2f(eAh[arow + 288 + i0]) + bf2f(eAl[arow + 288 + i0]);
        if (i1 < DEC) hdv1 = bf2f(eAh[arow + 288 + i1]) + bf2f(eAl[arow + 288 + i1]);
        if (t < NF * NF) wv0 = wvec[(size_t)item * (NF * NF) + t];
    }
    {
        // per-wave quarter; each instr: 64 lanes x 16B = 1 KiB, linear dest
        const float* csrc = c + (size_t)item * IMG + wave * 1024 + lane * 4;
        const float* xsrc = x + (size_t)item * IMG + wave * 1024 + lane * 4;
        float* cdst = cc + wave * 1024;
        float* xdst = xx + wave * 1024;
#pragma unroll
        for (int j = 0; j < 4; ++j) {
            __builtin_amdgcn_global_load_lds(
                (const __attribute__((address_space(1))) void*)(csrc + j * 256),
                (__attribute__((address_space(3))) void*)(cdst + j * 256), 16, 0, 0);
            __builtin_amdgcn_global_load_lds(
                (const __attribute__((address_space(1))) void*)(xsrc + j * 256),
                (__attribute__((address_space(3))) void*)(xdst + j * 256), 16, 0, 0);
        }
    }
    hd[t] = hdv0;
    if (t + 256 < DEC) hd[t + 256] = hdv1;
    if (t < NF * NF) wsv[t] = wv0;
    bar_lds();

    // --- phase 1: attention (shared by write & next glimpse) + u ---
    attn_compute_nb(hd, w_attn, b_attn, p, Fx, Fy, rowinv);
    bar_lds();
    const float gamma = expf(p[4]);
    const float ginv = 1.f / gamma;
    for (int e = t; e < 64 * NF; e += 256) {
        const int Bb = e / 12, m = e - (e / 12) * 12;
        float s = 0.f;
#pragma unroll
        for (int n = 0; n < 12; ++n) s += Fy[n][Bb] * wsv[n * 12 + m];
        u[Bb][m] = s;
    }

    // --- phase 2: canvas update + imgh (needs prefetched xx/cc: full sync) ---
    __syncthreads();   // drains vmcnt -> xx/cc valid; also covers u
#pragma unroll
    for (int j = 0; j < 4; ++j) {
        const int i0 = j * 1024 + t * 4;
        const int Bb = i0 >> 6, a0 = i0 & 63;
        float s0 = 0, s1 = 0, s2 = 0, s3 = 0;
#pragma unroll
        for (int m = 0; m < 12; ++m) {
            const float um = u[Bb][m];
            s0 += um * Fx[m][a0];     s1 += um * Fx[m][a0 + 1];
            s2 += um * Fx[m][a0 + 2]; s3 += um * Fx[m][a0 + 3];
        }
        const float4 cv = *(const float4*)&cc[i0];
        const float4 cn = make_float4(cv.x + s0 * ginv, cv.y + s1 * ginv,
                                      cv.z + s2 * ginv, cv.w + s3 * ginv);
        *(float4*)&c[(size_t)item * IMG + i0] = cn;
        const float4 xv = *(const float4*)&xx[i0];
        *(float4*)&cc[i0] = make_float4(xv.x - sigmoidf_(cn.x), xv.y - sigmoidf_(cn.y),
                                        xv.z - sigmoidf_(cn.z), xv.w - sigmoidf_(cn.w));
    }
    bar_lds();

    // --- phase 3: glimpse for step t+1 (img=xx, x_hat=cc) ---
    if (t < 192) {
        const int n = t >> 4, a0 = (t & 15) * 4;
        float s10 = 0, s11 = 0, s12 = 0, s13 = 0;
        float s20 = 0, s21 = 0, s22 = 0, s23 = 0;
        for (int Bi = 0; Bi < 64; ++Bi) {
            const float fy = Fy[n][Bi];
            const float4 v1 = *(const float4*)&xx[Bi * 64 + a0];
            const float4 v2 = *(const float4*)&cc[Bi * 64 + a0];
            s10 += fy * v1.x; s11 += fy * v1.y; s12 += fy * v1.z; s13 += fy * v1.w;
            s20 += fy * v2.x; s21 += fy * v2.y; s22 += fy * v2.z; s23 += fy * v2.w;
        }
        *(float4*)&tmp1[n][a0] = make_float4(s10, s11, s12, s13);
        *(float4*)&tmp2[n][a0] = make_float4(s20, s21, s22, s23);
    }
    bar_lds();
    for (int e = t; e < 2 * NF * NF; e += 256) {
        const int which = e / 144;
        const int idx = e - which * 144;
        const int n = idx / 12, m = idx - (idx / 12) * 12;
        const float (*tp)[68] = which ? tmp2 : tmp1;
        const float4* tv = (const float4*)&tp[n][0];
        const float4* fv = (const float4*)&Fx[m][0];
        float s = 0.f;
#pragma unroll
        for (int a4 = 0; a4 < 16; ++a4) {
            const float4 tvv = tv[a4], fvv = fv[a4];
            s += tvv.x * fvv.x + tvv.y * fvv.y + tvv.z * fvv.z + tvv.w * fvv.w;
        }
        unsigned short vh, vl;
        split2(s * gamma, vh, vl);
        eAh[arow + e] = vh;
        eAl[arow + e] = vl;
    }
}

// ---------------------------------------------------------------------------
// LSTM elementwise; writes h as bf16 hi/lo into 1 or 2 cat-A destinations.
// ---------------------------------------------------------------------------
__global__ __launch_bounds__(256) void k_lstm(
    const float* __restrict__ gates, float* __restrict__ s,
    unsigned short* __restrict__ d1h, unsigned short* __restrict__ d1l, int ld1,
    unsigned short* __restrict__ d2h, unsigned short* __restrict__ d2l, int ld2)
{
    const int idx = blockIdx.x * 256 + threadIdx.x;
    if (idx >= BATCH * ENC) return;
    const int m = idx / ENC, n = idx - m * ENC;
    const float* g = gates + (size_t)m * GDIM;
    const float gi = g[n], gf = g[n + 400], gg = g[n + 800], go = g[n + 1200];
    const float cold = s[idx];
    const float c2 = sigmoidf_(gf) * cold + sigmoidf_(gi) * tanhf(gg);
    s[idx] = c2;
    const float h = sigmoidf_(go) * tanhf(c2);
    unsigned short hh, hl;
    split2(h, hh, hl);
    d1h[(size_t)m * ld1 + n] = hh;
    d1l[(size_t)m * ld1 + n] = hl;
    if (d2h) {
        d2h[(size_t)m * ld2 + n] = hh;
        d2l[(size_t)m * ld2 + n] = hl;
    }
}

// z = mu + exp(logsig)*eps -> decA cols 0:100 (hi/lo)
__global__ __launch_bounds__(256) void k_zelem(
    const float* __restrict__ mus, const float* __restrict__ eps_t,
    unsigned short* __restrict__ dzh, unsigned short* __restrict__ dzl)
{
    const int idx = blockIdx.x * 256 + threadIdx.x;
    if (idx >= BATCH * ZS) return;
    const int m = idx / ZS, o = idx - m * ZS;
    const float zv = mus[(size_t)m * 200 + o] + expf(mus[(size_t)m * 200 + 100 + o]) * eps_t[idx];
    unsigned short h, l;
    split2(zv, h, l);
    dzh[(size_t)m * KDEC + o] = h;
    dzl[(size_t)m * KDEC + o] = l;
}

// ---------------------------------------------------------------------------
// Write (final step only): attn(h_dec), wr = Fy^T @ w @ Fx / gamma, c += wr.
// ---------------------------------------------------------------------------
__global__ __launch_bounds__(256) void k_write(
    const unsigned short* __restrict__ eAh, const unsigned short* __restrict__ eAl,
    const float* __restrict__ w_attn, const float* __restrict__ b_attn,
    const float* __restrict__ wvec,
    float* __restrict__ c)
{
    __shared__ __align__(16) float hd[DEC];
    __shared__ __align__(16) float p[8];
    __shared__ __align__(16) float Fx[NF][68], Fy[NF][68];
    __shared__ __align__(16) float rowinv[24];
    __shared__ __align__(16) float wsv[NF * NF];
    __shared__ __align__(16) float u[64][13];
    const int item = blockIdx.x;
    const int t = threadIdx.x;
    const size_t arow = (size_t)item * KENC;

    for (int i = t; i < DEC; i += 256)
        hd[i] = bf2f(eAh[arow + 288 + i]) + bf2f(eAl[arow + 288 + i]);
    if (t < NF * NF) wsv[t] = wvec[(size_t)item * (NF * NF) + t];
    __syncthreads();
    attn_compute(hd, w_attn, b_attn, p, Fx, Fy, rowinv);
    __syncthreads();
    const float ginv = 1.f / expf(p[4]);

    for (int e = t; e < 64 * NF; e += 256) {
        const int Bb = e / 12, m = e - (e / 12) * 12;
        float s = 0.f;
#pragma unroll
        for (int n = 0; n < 12; ++n) s += Fy[n][Bb] * wsv[n * 12 + m];
        u[Bb][m] = s;
    }
    __syncthreads();
    for (int i = t; i < IMG; i += 256) {
        const int Bb = i >> 6, a = i & 63;
        float s = 0.f;
#pragma unroll
        for (int m = 0; m < 12; ++m) s += u[Bb][m] * Fx[m][a];
        c[(size_t)item * IMG + i] += s * ginv;
    }
}

// ---------------------------------------------------------------------------
extern "C" void kernel_launch(void* const* d_in, const int* in_sizes, int n_in,
                              void* d_out, int out_size, void* d_ws, size_t ws_size,
                              hipStream_t stream)
{
    const float* x        = (const float*)d_in[0];
    const float* eps      = (const float*)d_in[1];
    const float* w_enc_ih = (const float*)d_in[2];
    const float* w_enc_hh = (const float*)d_in[3];
    const float* b_enc_ih = (const float*)d_in[4];
    const float* b_enc_hh = (const float*)d_in[5];
    const float* w_dec_ih = (const float*)d_in[6];
    const float* w_dec_hh = (const float*)d_in[7];
    const float* b_dec_ih = (const float*)d_in[8];
    const float* b_dec_hh = (const float*)d_in[9];
    const float* w_mu     = (const float*)d_in[10];
    const float* b_mu     = (const float*)d_in[11];
    const float* w_sig    = (const float*)d_in[12];
    const float* b_sig    = (const float*)d_in[13];
    const float* w_attn   = (const float*)d_in[14];
    const float* b_attn   = (const float*)d_in[15];
    const float* w_write  = (const float*)d_in[16];
    const float* b_write  = (const float*)d_in[17];

    float* canvas = (float*)d_out;

    // ---- workspace layout (256B-aligned chunks) ----
    uint8_t* p = (uint8_t*)d_ws;
    auto nextu = [&](size_t elems) {
        unsigned short* r = (unsigned short*)p;
        p += (elems * 2 + 255) & ~(size_t)255;
        return r;
    };
    auto nextf = [&](size_t elems) {
        float* r = (float*)p;
        p += (elems * 4 + 255) & ~(size_t)255;
        return r;
    };
    uint8_t* zstart = p;
    unsigned short* encA_h = nextu((size_t)(BATCH + 1) * KENC);
    unsigned short* encA_l = nextu((size_t)(BATCH + 1) * KENC);
    unsigned short* decA_h = nextu((size_t)(BATCH + 1) * KDEC);
    unsigned short* decA_l = nextu((size_t)(BATCH + 1) * KDEC);
    unsigned short* encB_h = nextu((size_t)NBIG * KENC);
    unsigned short* encB_l = nextu((size_t)NBIG * KENC);
    unsigned short* decB_h = nextu((size_t)NBIG * KDEC);
    unsigned short* decB_l = nextu((size_t)NBIG * KDEC);
    unsigned short* musB_h = nextu((size_t)NSML * KSML);
    unsigned short* musB_l = nextu((size_t)NSML * KSML);
    unsigned short* wrtB_h = nextu((size_t)NSML * KSML);
    unsigned short* wrtB_l = nextu((size_t)NSML * KSML);
    float* s_enc = nextf((size_t)BATCH * ENC);
    float* s_dec = nextf((size_t)BATCH * DEC);
    float* b_cat = nextf(256);
    uint8_t* zend = p;
    float* gates = nextf((size_t)BATCH * GDIM);
    float* mus   = nextf((size_t)BATCH * 200);
    float* wvec  = nextf((size_t)BATCH * (NF * NF));

    hipMemsetAsync(zstart, 0, (size_t)(zend - zstart), stream);
    hipMemsetAsync(canvas, 0, (size_t)BATCH * IMG * sizeof(float), stream);

    // weight pre-split (runs every launch; ws is re-poisoned each call)
    auto fill = [&](const float* src, int rows, int cols,
                    unsigned short* dh, unsigned short* dl, int ld, int col0, int row0) {
        k_fillw<<<dim3((rows * cols + 255) / 256), 256, 0, stream>>>(
            src, rows, cols, dh, dl, ld, col0, row0);
    };
    fill(w_enc_ih, 1600, 688, encB_h, encB_l, KENC, 0, 0);
    fill(w_enc_hh, 1600, 400, encB_h, encB_l, KENC, 688, 0);
    fill(w_dec_ih, 1600, 100, decB_h, decB_l, KDEC, 0, 0);
    fill(w_dec_hh, 1600, 400, decB_h, decB_l, KDEC, 128, 0);
    fill(w_mu,     100, 400, musB_h, musB_l, KSML, 0, 0);
    fill(w_sig,    100, 400, musB_h, musB_l, KSML, 0, 100);
    fill(w_write,  144, 400, wrtB_h, wrtB_l, KSML, 0, 0);
    hipMemcpyAsync(b_cat,       b_mu,  100 * 4, hipMemcpyDeviceToDevice, stream);
    hipMemcpyAsync(b_cat + 100, b_sig, 100 * 4, hipMemcpyDeviceToDevice, stream);

    const dim3 blk(256);
    // glimpse for step 0 (h_dec=0, canvas=0)
    k_glimpse<<<BATCH, blk, 0, stream>>>(x, canvas, encA_h, encA_l, w_attn, b_attn);
    for (int t = 0; t < T_STEPS; ++t) {
        // encoder gates: encA @ encB^T
        k_gemm2<<<dim3(13, 32), blk, 0, stream>>>(encA_h, encA_l, KENC, 0,
            encB_h, encB_l, KENC, b_enc_ih, b_enc_hh, gates, GDIM);
        // encoder LSTM: h_enc -> encA[:,688:1088]
        k_lstm<<<dim3((BATCH * ENC + 255) / 256), blk, 0, stream>>>(gates, s_enc,
            encA_h + 688, encA_l + 688, KENC, nullptr, nullptr, 0);
        // mu/logsig: h_enc (encA cols 688+) @ musB^T
        k_gemm2<<<dim3(2, 32), blk, 0, stream>>>(encA_h, encA_l, KENC, 688,
            musB_h, musB_l, KSML, b_cat, nullptr, mus, 200);
        // z -> decA[:,0:100]
        k_zelem<<<dim3((BATCH * ZS + 255) / 256), blk, 0, stream>>>(
            mus, eps + (size_t)t * BATCH * ZS, decA_h, decA_l);
        // decoder gates: decA @ decB^T
        k_gemm2<<<dim3(13, 32), blk, 0, stream>>>(decA_h, decA_l, KDEC, 0,
            decB_h, decB_l, KDEC, b_dec_ih, b_dec_hh, gates, GDIM);
        // decoder LSTM: h_dec -> encA[:,288:688] and decA[:,128:528]
        k_lstm<<<dim3((BATCH * ENC + 255) / 256), blk, 0, stream>>>(gates, s_dec,
            encA_h + 288, encA_l + 288, KENC, decA_h + 128, decA_l + 128, KDEC);
        // write vector: h_dec (encA cols 288+) @ wrtB^T
        k_gemm2<<<dim3(2, 32), blk, 0, stream>>>(encA_h, encA_l, KENC, 288,
            wrtB_h, wrtB_l, KSML, b_write, nullptr, wvec, NF * NF);
        if (t < T_STEPS - 1) {
            // fused: canvas += write(t); r(t+1) = glimpse (shared attention)
            k_wrgl<<<BATCH, blk, 0, stream>>>(x, canvas, encA_h, encA_l,
                                              w_attn, b_attn, wvec);
        } else {
            // final step: write only
            k_write<<<BATCH, blk, 0, stream>>>(encA_h, encA_l, w_attn, b_attn,
                                               wvec, canvas);
        }
    }
}